// Round 8
// baseline (129.544 us; speedup 1.0000x reference)
//
#include <hip/hip_runtime.h>
#include <math.h>

#define BB 4
#define LL 1024
#define DD 1024
#define KK 20
#define CC 21
#define LC (LL * CC)          // 21504 floats per (b, i) output row-panel
#define NQ (LC / 4)           // 5376 float4 per panel

typedef float vf4 __attribute__((ext_vector_type(4)));   // native vec for NT store

#define DOT4(a, b) ((a).x*(b).x + (a).y*(b).y + (a).z*(b).z + (a).w*(b).w)

__device__ __forceinline__ float wave_reduce_sum(float v) {
    #pragma unroll
    for (int off = 1; off < 64; off <<= 1)
        v += __shfl_xor(v, off, 64);
    return v;
}

// ---------------------------------------------------------------------------
// Kernel 0: zd[k,c] = dic[k,:] . Wz_w[c,:] + Wz_b[c]       (e in [0,420))
//           M [k,c] = dic[k,:] . cs_w[c, D:2D]             (e in [420,840))
// ---------------------------------------------------------------------------
__global__ __launch_bounds__(64) void k0_zdM(
    const float* __restrict__ dic,
    const float* __restrict__ Wz_w, const float* __restrict__ Wz_b,
    const float* __restrict__ cs_w,
    float* __restrict__ zd, float* __restrict__ M)
{
    int e = blockIdx.x;                 // 0..2*K*C-1
    int lane = threadIdx.x;
    bool isM = (e >= KK * CC);
    int e2 = isM ? e - KK * CC : e;
    int k = e2 / CC, c = e2 % CC;
    const float* a = dic + k * DD;
    const float* w = isM ? (cs_w + (size_t)c * (2 * DD) + DD) : (Wz_w + c * DD);
    float p = 0.f;
    #pragma unroll
    for (int i = 0; i < DD / 64; ++i) {
        int d = lane + 64 * i;
        p += a[d] * w[d];
    }
    p = wave_reduce_sum(p);
    if (lane == 0) {
        if (isM) M[e2] = p;
        else     zd[e2] = p + Wz_b[c];
    }
}

// ---------------------------------------------------------------------------
// Kernel 1 v4: 4 rows per single-wave block, 1024 blocks (ALL resident:
// 4 blocks/CU, LDS cap 5). Weight panel amortized over 4 rows. Partials
// split by c-phase so one 22.8 KB trP buffer suffices:
//   phase 1: c=0..20 (Wy_w)    -> trP -> reduce -> fin[r][c]   (+Wy_b)
//   phase 2: c=0..20 (cs_w 1st)-> trP -> reduce -> fin[r][22+c]
// trP[lane*89 + c*4 + r]: write banks 25*lane mod 32 -> 2-way (free);
// reduce read <=3-way on a tiny phase. No register partial arrays.
// ---------------------------------------------------------------------------
__global__ __launch_bounds__(64) void k1_rows(
    const float* __restrict__ x,
    const float* __restrict__ prior,
    const float* __restrict__ Wy_w, const float* __restrict__ Wy_b,
    const float* __restrict__ cs_w, const float* __restrict__ cs_b,
    const float* __restrict__ zd, const float* __restrict__ M,
    float* __restrict__ ly_ws, float* __restrict__ lz_ws)
{
    const int lane = threadIdx.x;
    const int r0 = blockIdx.x * 4;

    __shared__ float zds[KK * CC];
    __shared__ float Ms[KK * CC];
    __shared__ float pr[KK];
    __shared__ float bias[2 * CC];      // [0..20]=Wy_b, [21..41]=cs_b
    __shared__ float trP[64 * 89];      // partial buffer, stride 89
    __shared__ float fin[4][44];        // [r][c]=yW+Wy_b, [r][22+c]=ly

    for (int i = lane; i < KK * CC; i += 64) { zds[i] = zd[i]; Ms[i] = M[i]; }
    if (lane < KK) pr[lane] = prior[lane];
    if (lane < CC) { bias[lane] = Wy_b[lane]; bias[CC + lane] = cs_b[lane]; }

    // 4 x-rows in registers (coalesced float4): 64 VGPR, live across phases
    float4 xR[4][4];
    #pragma unroll
    for (int r = 0; r < 4; ++r) {
        const float4* xp = reinterpret_cast<const float4*>(x + (size_t)(r0 + r) * DD);
        #pragma unroll
        for (int i = 0; i < 4; ++i) xR[r][i] = xp[lane + 64 * i];
    }
    __syncthreads();

    // ================= phase 1: Wy_w =================
    #pragma unroll
    for (int c = 0; c < CC; ++c) {
        const float4* w4 = reinterpret_cast<const float4*>(Wy_w + (size_t)c * DD);
        float4 w0 = w4[lane], w1 = w4[lane + 64], w2 = w4[lane + 128], w3 = w4[lane + 192];
        #pragma unroll
        for (int r = 0; r < 4; ++r) {
            trP[lane * 89 + c * 4 + r] =
                DOT4(xR[r][0], w0) + DOT4(xR[r][1], w1) +
                DOT4(xR[r][2], w2) + DOT4(xR[r][3], w3);
        }
    }
    __syncthreads();
    #pragma unroll
    for (int p = 0; p < 2; ++p) {       // sub-pass p: rows 2p, 2p+1
        if (lane < 2 * CC) {
            int c = lane >> 1, r = 2 * p + (lane & 1);
            int off = c * 4 + r;
            float a0 = 0.f, a1 = 0.f, a2 = 0.f, a3 = 0.f;
            #pragma unroll
            for (int j = 0; j < 64; j += 4) {
                a0 += trP[(j + 0) * 89 + off];
                a1 += trP[(j + 1) * 89 + off];
                a2 += trP[(j + 2) * 89 + off];
                a3 += trP[(j + 3) * 89 + off];
            }
            fin[r][c] = (a0 + a1) + (a2 + a3) + bias[c];
        }
    }
    __syncthreads();

    // ================= phase 2: cs_w first halves =================
    #pragma unroll
    for (int c = 0; c < CC; ++c) {
        const float4* w4 = reinterpret_cast<const float4*>(cs_w + (size_t)c * (2 * DD));
        float4 w0 = w4[lane], w1 = w4[lane + 64], w2 = w4[lane + 128], w3 = w4[lane + 192];
        #pragma unroll
        for (int r = 0; r < 4; ++r) {
            trP[lane * 89 + c * 4 + r] =
                DOT4(xR[r][0], w0) + DOT4(xR[r][1], w1) +
                DOT4(xR[r][2], w2) + DOT4(xR[r][3], w3);
        }
    }
    __syncthreads();
    #pragma unroll
    for (int p = 0; p < 2; ++p) {
        if (lane < 2 * CC) {
            int c = lane >> 1, r = 2 * p + (lane & 1);
            int off = c * 4 + r;
            float a0 = 0.f, a1 = 0.f, a2 = 0.f, a3 = 0.f;
            #pragma unroll
            for (int j = 0; j < 64; j += 4) {
                a0 += trP[(j + 0) * 89 + off];
                a1 += trP[(j + 1) * 89 + off];
                a2 += trP[(j + 2) * 89 + off];
                a3 += trP[(j + 3) * 89 + off];
            }
            fin[r][22 + c] = (a0 + a1) + (a2 + a3);   // ly: no bias
        }
    }
    __syncthreads();

    // ===== softmax + lz: half-wave per row, two iterations for 4 rows =====
    const float scale = 0.21821789023599238f;   // 1/sqrt(21)
    #pragma unroll
    for (int rr = 0; rr < 4; rr += 2) {
        int row = rr + (lane >> 5);
        int cc  = lane & 31;
        const float* f = fin[row];

        float s[KK];
        float m = -1e30f;
        #pragma unroll
        for (int k = 0; k < KK; ++k) {
            float t = 0.f;
            #pragma unroll
            for (int c = 0; c < CC; ++c) t += f[c] * zds[k * CC + c];
            s[k] = t * scale;
            m = fmaxf(m, s[k]);
        }
        float sum = 0.f;
        #pragma unroll
        for (int k = 0; k < KK; ++k) { s[k] = expf(s[k] - m); sum += s[k]; }
        float inv = 1.f / sum;

        if (cc < CC) {
            float lzv = bias[CC + cc];              // cs_b
            #pragma unroll
            for (int k = 0; k < KK; ++k) lzv += s[k] * inv * pr[k] * Ms[k * CC + cc];
            size_t r = (size_t)(r0 + row);
            ly_ws[r * CC + cc] = f[22 + cc];
            lz_ws[r * CC + cc] = lzv;
        }
    }
}

// ---------------------------------------------------------------------------
// Kernel 2: outer-sum write (measured at write roofline ~6.5 TB/s) — unchanged.
// ---------------------------------------------------------------------------
__global__ __launch_bounds__(512) void k2_outer(
    const float* __restrict__ ly_ws, const float* __restrict__ lz_ws,
    float* __restrict__ out)
{
    int tid = threadIdx.x;
    int blk = blockIdx.x;               // 0..1023
    int b  = blk >> 8;                  // 256 blocks per image
    int i0 = (blk & 255) << 2;          // * 4 panels

    __shared__ vf4 lyp4[4 * CC];
    {
        float* lyp = reinterpret_cast<float*>(lyp4);
        if (tid < 4 * 84) {
            int i = tid / 84, f = tid % 84;
            lyp[i * 84 + f] = ly_ws[(size_t)(b * LL + i0 + i) * CC + (f % 21)];
        }
    }

    const float* lzp = lz_ws + (size_t)b * LC;
    vf4 lzv[11];
    #pragma unroll
    for (int it = 0; it < 11; ++it) {
        int idx = tid + it * 512;
        if (idx < NQ) {
            lzv[it] = *reinterpret_cast<const vf4*>(lzp + (size_t)idx * 4);
        } else {
            lzv[it] = (vf4){0.f, 0.f, 0.f, 0.f};
        }
    }
    __syncthreads();

    int g0 = tid % 21;                  // (tid + it*512) % 21 steps by +8 mod 21

    #pragma unroll
    for (int i = 0; i < 4; ++i) {
        float* op = out + (size_t)(b * LL + i0 + i) * LC;
        const vf4* lyp_i = lyp4 + i * CC;
        int g = g0;
        #pragma unroll
        for (int it = 0; it < 11; ++it) {
            int idx = tid + it * 512;
            if (idx < NQ) {
                vf4 o = lzv[it] + lyp_i[g];
                __builtin_nontemporal_store(o, reinterpret_cast<vf4*>(op + (size_t)idx * 4));
            }
            g += 8; if (g >= 21) g -= 21;
        }
    }
}

extern "C" void kernel_launch(void* const* d_in, const int* in_sizes, int n_in,
                              void* d_out, int out_size, void* d_ws, size_t ws_size,
                              hipStream_t stream)
{
    const float* x     = (const float*)d_in[0];
    const float* dic   = (const float*)d_in[1];
    const float* prior = (const float*)d_in[2];
    const float* Wy_w  = (const float*)d_in[3];
    const float* Wy_b  = (const float*)d_in[4];
    const float* Wz_w  = (const float*)d_in[5];
    const float* Wz_b  = (const float*)d_in[6];
    const float* cs_w  = (const float*)d_in[7];
    const float* cs_b  = (const float*)d_in[8];
    float* out = (float*)d_out;

    float* ws = (float*)d_ws;
    float* zd = ws;                       // 420 floats
    float* M  = ws + 512;                 // 420 floats
    float* ly = ws + 1024;                // B*L*C = 86016 floats
    float* lz = ly + BB * LL * CC;        // 86016 floats

    k0_zdM <<<dim3(2 * KK * CC), dim3(64),  0, stream>>>(dic, Wz_w, Wz_b, cs_w, zd, M);
    k1_rows<<<dim3(BB * LL / 4), dim3(64),  0, stream>>>(x, prior, Wy_w, Wy_b, cs_w, cs_b,
                                                         zd, M, ly, lz);
    k2_outer<<<dim3(BB * LL / 4), dim3(512), 0, stream>>>(ly, lz, out);
}

// Round 9
// 101.496 us; speedup vs baseline: 1.2764x; 1.2764x over previous
//
#include <hip/hip_runtime.h>
#include <math.h>

#define BB 4
#define LL 1024
#define DD 1024
#define KK 20
#define CC 21
#define LC (LL * CC)          // 21504 floats per (b, i) output row-panel
#define NQ (LC / 4)           // 5376 float4 per panel

typedef float vf4   __attribute__((ext_vector_type(4)));   // native vec for NT store
typedef short bf16x8 __attribute__((ext_vector_type(8)));  // MFMA A/B frag (8 bf16)
typedef float f32x4  __attribute__((ext_vector_type(4)));  // MFMA C/D frag

__device__ __forceinline__ unsigned short f2bf(float f) {  // RNE f32->bf16
    unsigned int u = __builtin_bit_cast(unsigned int, f);
    u += 0x7FFFu + ((u >> 16) & 1u);
    return (unsigned short)(u >> 16);
}

__device__ __forceinline__ float wave_reduce_sum(float v) {
    #pragma unroll
    for (int off = 1; off < 64; off <<= 1)
        v += __shfl_xor(v, off, 64);
    return v;
}

// ---------------------------------------------------------------------------
// Kernel 0: blocks 0..839: zd[k,c], M[k,c] (fp32 dots, one wave per entry).
//           blocks 840..863: build Wcat bf16 [48][1024]:
//             rows 0..20 = Wy_w, 21..41 = cs_w[:, :D], 42..47 = 0.
// ---------------------------------------------------------------------------
__global__ __launch_bounds__(64) void k0_zdM(
    const float* __restrict__ dic,
    const float* __restrict__ Wz_w, const float* __restrict__ Wz_b,
    const float* __restrict__ cs_w, const float* __restrict__ Wy_w,
    float* __restrict__ zd, float* __restrict__ M,
    unsigned short* __restrict__ Wcat)
{
    int blk = blockIdx.x;
    int lane = threadIdx.x;

    if (blk < 2 * KK * CC) {
        bool isM = (blk >= KK * CC);
        int e2 = isM ? blk - KK * CC : blk;
        int k = e2 / CC, c = e2 % CC;
        const float* a = dic + k * DD;
        const float* w = isM ? (cs_w + (size_t)c * (2 * DD) + DD) : (Wz_w + c * DD);
        float p = 0.f;
        #pragma unroll
        for (int i = 0; i < DD / 64; ++i) {
            int d = lane + 64 * i;
            p += a[d] * w[d];
        }
        p = wave_reduce_sum(p);
        if (lane == 0) {
            if (isM) M[e2] = p;
            else     zd[e2] = p + Wz_b[c];
        }
    } else {
        int e2 = blk - 2 * KK * CC;       // 0..23, each converts 2048 elems
        int base = e2 * 2048;
        #pragma unroll
        for (int t = 0; t < 32; ++t) {
            int i = base + lane + 64 * t;
            int c = i >> 10, k = i & 1023;
            float v;
            if (c < CC)          v = Wy_w[(size_t)c * DD + k];
            else if (c < 2 * CC) v = cs_w[(size_t)(c - CC) * (2 * DD) + k];
            else                 v = 0.f;
            Wcat[i] = f2bf(v);
        }
    }
}

// ---------------------------------------------------------------------------
// Kernel 1 (MFMA): one wave per 16-row tile, 256 blocks (1/CU).
//   acc[3] = x_tile(16x1024, bf16 in-flight) @ Wcat^T (48x1024 bf16)
//   via 16x16x32 MFMA, K-loop 32 steps, 3 col-tiles.
//   Frag layout (m89/m97 convention): A lane reads x[r0+(l&15)][k0+(l>>4)*8..+8],
//   B lane reads Wcat[c0+(l&15)][k0+(l>>4)*8..+8], D: col=l&15, row=(l>>4)*4+j.
//   Epilogue: D -> LDS yT[16][49] -> in-wave softmax (row=lane&15, redundant
//   over lane>>4) -> lz via M, stores ly/lz.
// ---------------------------------------------------------------------------
__global__ __launch_bounds__(64) void k1_mfma(
    const float* __restrict__ x,
    const float* __restrict__ prior,
    const float* __restrict__ Wy_b, const float* __restrict__ cs_b,
    const unsigned short* __restrict__ Wcat,
    const float* __restrict__ zd, const float* __restrict__ M,
    float* __restrict__ ly_ws, float* __restrict__ lz_ws)
{
    const int lane = threadIdx.x;
    const int r0 = blockIdx.x * 16;

    __shared__ float zds[KK * CC];
    __shared__ float Ms[KK * CC];
    __shared__ float pr[KK];
    __shared__ float bias[2 * CC];      // [0..20]=Wy_b, [21..41]=cs_b
    __shared__ float yT[16][49];

    for (int i = lane; i < KK * CC; i += 64) { zds[i] = zd[i]; Ms[i] = M[i]; }
    if (lane < KK) pr[lane] = prior[lane];
    if (lane < CC) { bias[lane] = Wy_b[lane]; bias[CC + lane] = cs_b[lane]; }

    const int fr = lane & 15;           // frag row (A) / col (B,D) index
    const int kg = lane >> 4;           // k-group 0..3

    const float*          xp  = x    + (size_t)(r0 + fr) * DD + kg * 8;
    const unsigned short* w0p = Wcat + (size_t)(fr +  0) * DD + kg * 8;
    const unsigned short* w1p = Wcat + (size_t)(fr + 16) * DD + kg * 8;
    const unsigned short* w2p = Wcat + (size_t)(fr + 32) * DD + kg * 8;

    f32x4 acc0 = {0.f, 0.f, 0.f, 0.f};
    f32x4 acc1 = {0.f, 0.f, 0.f, 0.f};
    f32x4 acc2 = {0.f, 0.f, 0.f, 0.f};

    #pragma unroll 4
    for (int ks = 0; ks < 32; ++ks) {
        float4 a0 = *reinterpret_cast<const float4*>(xp + ks * 32);
        float4 a1 = *reinterpret_cast<const float4*>(xp + ks * 32 + 4);
        bf16x8 af;
        af[0] = (short)f2bf(a0.x); af[1] = (short)f2bf(a0.y);
        af[2] = (short)f2bf(a0.z); af[3] = (short)f2bf(a0.w);
        af[4] = (short)f2bf(a1.x); af[5] = (short)f2bf(a1.y);
        af[6] = (short)f2bf(a1.z); af[7] = (short)f2bf(a1.w);
        bf16x8 b0 = *reinterpret_cast<const bf16x8*>(w0p + ks * 32);
        bf16x8 b1 = *reinterpret_cast<const bf16x8*>(w1p + ks * 32);
        bf16x8 b2 = *reinterpret_cast<const bf16x8*>(w2p + ks * 32);
        acc0 = __builtin_amdgcn_mfma_f32_16x16x32_bf16(af, b0, acc0, 0, 0, 0);
        acc1 = __builtin_amdgcn_mfma_f32_16x16x32_bf16(af, b1, acc1, 0, 0, 0);
        acc2 = __builtin_amdgcn_mfma_f32_16x16x32_bf16(af, b2, acc2, 0, 0, 0);
    }

    // D -> LDS: row = kg*4+j, col = fr (+0/16/32 per tile)
    #pragma unroll
    for (int j = 0; j < 4; ++j) {
        yT[kg * 4 + j][fr]      = acc0[j];
        yT[kg * 4 + j][16 + fr] = acc1[j];
        yT[kg * 4 + j][32 + fr] = acc2[j];
    }
    __syncthreads();

    // softmax for row fr (4-way redundant over kg), then lz for c = kg::4
    const float* f = yT[fr];
    const float scale = 0.21821789023599238f;   // 1/sqrt(21)
    float s[KK];
    float m = -1e30f;
    #pragma unroll
    for (int k = 0; k < KK; ++k) {
        float t = 0.f;
        #pragma unroll
        for (int c = 0; c < CC; ++c) t += (f[c] + bias[c]) * zds[k * CC + c];
        s[k] = t * scale;
        m = fmaxf(m, s[k]);
    }
    float sum = 0.f;
    #pragma unroll
    for (int k = 0; k < KK; ++k) { s[k] = expf(s[k] - m); sum += s[k]; }
    float inv = 1.f / sum;
    float wk[KK];
    #pragma unroll
    for (int k = 0; k < KK; ++k) wk[k] = s[k] * inv * pr[k];

    size_t rr = (size_t)(r0 + fr);
    for (int c = kg; c < CC; c += 4) {
        float lzv = bias[CC + c];                   // cs_b
        #pragma unroll
        for (int k = 0; k < KK; ++k) lzv += wk[k] * Ms[k * CC + c];
        ly_ws[rr * CC + c] = f[CC + c];             // yT col 21+c
        lz_ws[rr * CC + c] = lzv;
    }
}

// ---------------------------------------------------------------------------
// Kernel 2: outer-sum write (measured at write roofline ~6.5 TB/s) — unchanged.
// ---------------------------------------------------------------------------
__global__ __launch_bounds__(512) void k2_outer(
    const float* __restrict__ ly_ws, const float* __restrict__ lz_ws,
    float* __restrict__ out)
{
    int tid = threadIdx.x;
    int blk = blockIdx.x;               // 0..1023
    int b  = blk >> 8;                  // 256 blocks per image
    int i0 = (blk & 255) << 2;          // * 4 panels

    __shared__ vf4 lyp4[4 * CC];
    {
        float* lyp = reinterpret_cast<float*>(lyp4);
        if (tid < 4 * 84) {
            int i = tid / 84, f = tid % 84;
            lyp[i * 84 + f] = ly_ws[(size_t)(b * LL + i0 + i) * CC + (f % 21)];
        }
    }

    const float* lzp = lz_ws + (size_t)b * LC;
    vf4 lzv[11];
    #pragma unroll
    for (int it = 0; it < 11; ++it) {
        int idx = tid + it * 512;
        if (idx < NQ) {
            lzv[it] = *reinterpret_cast<const vf4*>(lzp + (size_t)idx * 4);
        } else {
            lzv[it] = (vf4){0.f, 0.f, 0.f, 0.f};
        }
    }
    __syncthreads();

    int g0 = tid % 21;                  // (tid + it*512) % 21 steps by +8 mod 21

    #pragma unroll
    for (int i = 0; i < 4; ++i) {
        float* op = out + (size_t)(b * LL + i0 + i) * LC;
        const vf4* lyp_i = lyp4 + i * CC;
        int g = g0;
        #pragma unroll
        for (int it = 0; it < 11; ++it) {
            int idx = tid + it * 512;
            if (idx < NQ) {
                vf4 o = lzv[it] + lyp_i[g];
                __builtin_nontemporal_store(o, reinterpret_cast<vf4*>(op + (size_t)idx * 4));
            }
            g += 8; if (g >= 21) g -= 21;
        }
    }
}

extern "C" void kernel_launch(void* const* d_in, const int* in_sizes, int n_in,
                              void* d_out, int out_size, void* d_ws, size_t ws_size,
                              hipStream_t stream)
{
    const float* x     = (const float*)d_in[0];
    const float* dic   = (const float*)d_in[1];
    const float* prior = (const float*)d_in[2];
    const float* Wy_w  = (const float*)d_in[3];
    const float* Wy_b  = (const float*)d_in[4];
    const float* Wz_w  = (const float*)d_in[5];
    const float* Wz_b  = (const float*)d_in[6];
    const float* cs_w  = (const float*)d_in[7];
    const float* cs_b  = (const float*)d_in[8];
    float* out = (float*)d_out;

    float* ws = (float*)d_ws;
    float* zd = ws;                       // 420 floats
    float* M  = ws + 512;                 // 420 floats
    float* ly = ws + 1024;                // B*L*C = 86016 floats
    float* lz = ly + BB * LL * CC;        // 86016 floats
    unsigned short* Wcat = (unsigned short*)(ws + 1024 + 2 * BB * LL * CC);  // 48*1024 bf16

    k0_zdM <<<dim3(2 * KK * CC + 24), dim3(64),  0, stream>>>(dic, Wz_w, Wz_b, cs_w, Wy_w,
                                                              zd, M, Wcat);
    k1_mfma<<<dim3(BB * LL / 16),     dim3(64),  0, stream>>>(x, prior, Wy_b, cs_b, Wcat,
                                                              zd, M, ly, lz);
    k2_outer<<<dim3(BB * LL / 4),     dim3(512), 0, stream>>>(ly, lz, out);
}